// Round 2
// baseline (2847.411 us; speedup 1.0000x reference)
//
#include <hip/hip_runtime.h>
#include <cstdint>
#include <cstddef>

#define N_NODES 100000
#define N_EDGES 1600000

// ---------------- workspace layout (byte offsets) ----------------
#define WS_ROWPTR   0            // (N+1) int
#define WS_DEG      400384       // N int
#define WS_FILL     800768       // N int
#define WS_INVDEG   1201152      // N float
#define WS_BSUM     1601536      // 98 int
#define WS_FLAG     1602560      // 1 int (1 = edge_index is int64)
#define WS_WLT0     1602816      // 128x128 f (transposed [k][o])
#define WS_WRT0     1668352
#define WS_WLT1     1733888
#define WS_WRT1     1799424
#define WS_WCT2     1864960      // 128x80 f ([k][o], o<40 -> Wl2, o>=40 -> Wr2)
#define WS_COL      1906176      // E int
#define WS_AGG      8306432      // N*128 f
#define WS_H1       59506432     // N*128 f
#define WS_H2       110706432    // N*128 f
#define WS_P        WS_AGG              // overlay (agg dead after layer-1 GEMM)
#define WS_R        (WS_AGG + 16000000) // N*40 f

__device__ __forceinline__ int edge_val(const void* ei, long long idx, int m64) {
    return m64 ? (int)((const long long*)ei)[idx] : ((const int*)ei)[idx];
}

// detect int32 vs int64 edge_index: int64 -> all odd 32-bit words are zero
__global__ void k_detect(const void* __restrict__ ei, int* __restrict__ flag) {
    __shared__ int s_any;
    if (threadIdx.x == 0) s_any = 0;
    __syncthreads();
    const int* p = (const int*)ei;
    int any = 0;
    for (int j = 0; j < 8; ++j) any |= p[2 * (threadIdx.x * 8 + j) + 1];
    if (any) s_any = 1;   // benign race: all writers write 1
    __syncthreads();
    if (threadIdx.x == 0) *flag = (s_any == 0) ? 1 : 0;
}

__global__ void k_transpose(const float* __restrict__ Wl0, const float* __restrict__ Wr0,
                            const float* __restrict__ Wl1, const float* __restrict__ Wr1,
                            const float* __restrict__ Wl2, const float* __restrict__ Wr2,
                            float* __restrict__ T0, float* __restrict__ T1,
                            float* __restrict__ T2, float* __restrict__ T3,
                            float* __restrict__ Tc) {
    int i = blockIdx.x * 256 + threadIdx.x;
    if (i < 16384) {
        int o = i >> 7, k = i & 127;
        int d = k * 128 + o;
        T0[d] = Wl0[i]; T1[d] = Wr0[i]; T2[d] = Wl1[i]; T3[d] = Wr1[i];
    }
    if (i < 10240) {
        int k = i / 80, o = i % 80;
        Tc[i] = (o < 40) ? Wl2[o * 128 + k] : Wr2[(o - 40) * 128 + k];
    }
}

__global__ void k_hist(const void* __restrict__ ei, const int* __restrict__ flag,
                       int* __restrict__ deg) {
    int m = *flag;
    int e = blockIdx.x * blockDim.x + threadIdx.x;
    if (e < N_EDGES) {
        int d = edge_val(ei, (long long)N_EDGES + e, m);
        atomicAdd(&deg[d], 1);
    }
}

__global__ void k_scan1(const int* __restrict__ deg, int* __restrict__ bsum) {
    __shared__ int sd[256];
    int t = threadIdx.x;
    int i0 = blockIdx.x * 1024 + t * 4;
    int s = 0;
    #pragma unroll
    for (int j = 0; j < 4; ++j) if (i0 + j < N_NODES) s += deg[i0 + j];
    sd[t] = s; __syncthreads();
    for (int off = 128; off; off >>= 1) {
        if (t < off) sd[t] += sd[t + off];
        __syncthreads();
    }
    if (t == 0) bsum[blockIdx.x] = sd[0];
}

__global__ void k_scan2(int* __restrict__ bsum, int* __restrict__ row_ptr, int nb) {
    if (threadIdx.x == 0 && blockIdx.x == 0) {
        int run = 0;
        for (int i = 0; i < nb; ++i) { int v = bsum[i]; bsum[i] = run; run += v; }
        row_ptr[N_NODES] = run;
    }
}

__global__ void k_scan3(const int* __restrict__ deg, const int* __restrict__ bsum,
                        int* __restrict__ row_ptr) {
    __shared__ int sd[256];
    int t = threadIdx.x;
    int i0 = blockIdx.x * 1024 + t * 4;
    int v[4]; int s = 0;
    #pragma unroll
    for (int j = 0; j < 4; ++j) { v[j] = (i0 + j < N_NODES) ? deg[i0 + j] : 0; s += v[j]; }
    sd[t] = s; __syncthreads();
    for (int off = 1; off < 256; off <<= 1) {
        int x = 0;
        if (t >= off) x = sd[t - off];
        __syncthreads();
        sd[t] += x;
        __syncthreads();
    }
    int run = bsum[blockIdx.x] + sd[t] - s;   // exclusive prefix for this thread
    #pragma unroll
    for (int j = 0; j < 4; ++j) {
        if (i0 + j < N_NODES) row_ptr[i0 + j] = run;
        run += v[j];
    }
}

__global__ void k_invdeg(const int* __restrict__ row_ptr, float* __restrict__ invd) {
    int i = blockIdx.x * 256 + threadIdx.x;
    if (i < N_NODES) {
        int d = row_ptr[i + 1] - row_ptr[i];
        invd[i] = 1.0f / (float)(d > 1 ? d : 1);
    }
}

__global__ void k_scatter(const void* __restrict__ ei, const int* __restrict__ flag,
                          const int* __restrict__ row_ptr, int* __restrict__ fill,
                          int* __restrict__ col) {
    int m = *flag;
    int e = blockIdx.x * blockDim.x + threadIdx.x;
    if (e < N_EDGES) {
        int s = edge_val(ei, e, m);
        int d = edge_val(ei, (long long)N_EDGES + e, m);
        int pos = row_ptr[d] + atomicAdd(&fill[d], 1);
        col[pos] = s;
    }
}

// mean-aggregate 128-dim rows: one wave per node, float2 per lane, 8 edges in flight
__global__ __launch_bounds__(256) void k_aggregate(
    const float* __restrict__ h, const int* __restrict__ rowp,
    const int* __restrict__ col, const float* __restrict__ invd,
    float* __restrict__ agg) {
    int w = blockIdx.x * 4 + (threadIdx.x >> 6);
    if (w >= N_NODES) return;
    int lane = threadIdx.x & 63;
    const float2* hp = (const float2*)h;
    int beg = rowp[w], end = rowp[w + 1];
    float x = 0.f, y = 0.f;
    int e = beg;
    for (; e + 8 <= end; e += 8) {
        int s0 = col[e], s1 = col[e + 1], s2 = col[e + 2], s3 = col[e + 3];
        int s4 = col[e + 4], s5 = col[e + 5], s6 = col[e + 6], s7 = col[e + 7];
        float2 a = hp[(size_t)s0 * 64 + lane];
        float2 b = hp[(size_t)s1 * 64 + lane];
        float2 c = hp[(size_t)s2 * 64 + lane];
        float2 d = hp[(size_t)s3 * 64 + lane];
        float2 a2 = hp[(size_t)s4 * 64 + lane];
        float2 b2 = hp[(size_t)s5 * 64 + lane];
        float2 c2 = hp[(size_t)s6 * 64 + lane];
        float2 d2 = hp[(size_t)s7 * 64 + lane];
        x += (a.x + b.x) + (c.x + d.x) + (a2.x + b2.x) + (c2.x + d2.x);
        y += (a.y + b.y) + (c.y + d.y) + (a2.y + b2.y) + (c2.y + d2.y);
    }
    for (; e + 4 <= end; e += 4) {
        int s0 = col[e], s1 = col[e + 1], s2 = col[e + 2], s3 = col[e + 3];
        float2 a = hp[(size_t)s0 * 64 + lane];
        float2 b = hp[(size_t)s1 * 64 + lane];
        float2 c = hp[(size_t)s2 * 64 + lane];
        float2 d = hp[(size_t)s3 * 64 + lane];
        x += (a.x + b.x) + (c.x + d.x);
        y += (a.y + b.y) + (c.y + d.y);
    }
    for (; e < end; ++e) {
        float2 a = hp[(size_t)col[e] * 64 + lane];
        x += a.x; y += a.y;
    }
    float id = invd[w];
    ((float2*)agg)[(size_t)w * 64 + lane] = make_float2(x * id, y * id);
}

// fused: out = relu(l2norm(agg@WlT + h@WrT + b)); 128 nodes/block, 512 thr
// thread: 4 outs (o4..o4+3) x 8 nodes; W staged in 32KB LDS chunks (K=64) so
// 4 blocks/CU fit (160/32) -> 32 waves/CU; V broadcast from L1
__global__ __launch_bounds__(512, 8) void k_gemm_fused(
    const float* __restrict__ agg, const float* __restrict__ hin,
    const float* __restrict__ WlT, const float* __restrict__ WrT,
    const float* __restrict__ bias, float* __restrict__ hout) {
    __shared__ float sW[64 * 128];   // 32 KB
    const int t = threadIdx.x;
    const int o4 = (t & 31) * 4;
    const int ng = t >> 5;                 // 0..15
    const int nb = blockIdx.x * 128 + ng * 8;

    float acc[8][4];
    const float4 bv = *(const float4*)(bias + o4);
    #pragma unroll
    for (int j = 0; j < 8; ++j) { acc[j][0] = bv.x; acc[j][1] = bv.y; acc[j][2] = bv.z; acc[j][3] = bv.w; }

    for (int ph = 0; ph < 2; ++ph) {
        const float* WT = ph ? WrT : WlT;
        const float* V  = ph ? hin : agg;
        const float4* vrow[8];
        #pragma unroll
        for (int j = 0; j < 8; ++j) {
            int n = nb + j; n = n < N_NODES ? n : N_NODES - 1;
            vrow[j] = (const float4*)(V + (size_t)n * 128);
        }
        for (int kh = 0; kh < 2; ++kh) {
            __syncthreads();
            const float4* wsrc = (const float4*)(WT + kh * 64 * 128);
            #pragma unroll
            for (int j = 0; j < 4; ++j)
                ((float4*)sW)[t + 512 * j] = wsrc[t + 512 * j];
            __syncthreads();
            #pragma unroll 4
            for (int kq = 0; kq < 16; ++kq) {
                const int k = kq * 4;
                float4 w0 = *(const float4*)(sW + (k + 0) * 128 + o4);
                float4 w1 = *(const float4*)(sW + (k + 1) * 128 + o4);
                float4 w2 = *(const float4*)(sW + (k + 2) * 128 + o4);
                float4 w3 = *(const float4*)(sW + (k + 3) * 128 + o4);
                #pragma unroll
                for (int j = 0; j < 8; ++j) {
                    float4 v = vrow[j][kh * 16 + kq];
                    acc[j][0] = fmaf(v.x, w0.x, fmaf(v.y, w1.x, fmaf(v.z, w2.x, fmaf(v.w, w3.x, acc[j][0]))));
                    acc[j][1] = fmaf(v.x, w0.y, fmaf(v.y, w1.y, fmaf(v.z, w2.y, fmaf(v.w, w3.y, acc[j][1]))));
                    acc[j][2] = fmaf(v.x, w0.z, fmaf(v.y, w1.z, fmaf(v.z, w2.z, fmaf(v.w, w3.z, acc[j][2]))));
                    acc[j][3] = fmaf(v.x, w0.w, fmaf(v.y, w1.w, fmaf(v.z, w2.w, fmaf(v.w, w3.w, acc[j][3]))));
                }
            }
        }
    }
    // epilogue: L2-normalize over the 128 outs (spread across 32 lanes), relu, store
    #pragma unroll
    for (int j = 0; j < 8; ++j) {
        int n = nb + j;
        float ss = acc[j][0] * acc[j][0] + acc[j][1] * acc[j][1]
                 + acc[j][2] * acc[j][2] + acc[j][3] * acc[j][3];
        #pragma unroll
        for (int m = 1; m < 32; m <<= 1) ss += __shfl_xor(ss, m, 64);
        float sc = 1.0f / fmaxf(sqrtf(ss), 1e-12f);
        float4 r = make_float4(fmaxf(acc[j][0] * sc, 0.f), fmaxf(acc[j][1] * sc, 0.f),
                               fmaxf(acc[j][2] * sc, 0.f), fmaxf(acc[j][3] * sc, 0.f));
        if (n < N_NODES) *(float4*)(hout + (size_t)n * 128 + o4) = r;
    }
}

// layer 2: P = h@Wl2T ; R = h@Wr2T + b2   (80 outs, cat-W in LDS)
__global__ __launch_bounds__(320, 2) void k_gemm2(
    const float* __restrict__ h, const float* __restrict__ WcatT,
    const float* __restrict__ b2, float* __restrict__ P, float* __restrict__ R) {
    __shared__ float sW[128 * 80];
    const int t = threadIdx.x;
    const int o4 = (t % 20) * 4;           // 0..76
    const int ng = t / 20;                 // 0..15
    const int nb = blockIdx.x * 128 + ng * 8;
    #pragma unroll
    for (int j = 0; j < 8; ++j)
        ((float4*)sW)[t + 320 * j] = ((const float4*)WcatT)[t + 320 * j];
    __syncthreads();
    float4 binit = make_float4(0.f, 0.f, 0.f, 0.f);
    if (o4 >= 40) binit = *(const float4*)(b2 + (o4 - 40));
    float acc[8][4];
    #pragma unroll
    for (int j = 0; j < 8; ++j) { acc[j][0] = binit.x; acc[j][1] = binit.y; acc[j][2] = binit.z; acc[j][3] = binit.w; }
    const float4* vrow[8];
    #pragma unroll
    for (int j = 0; j < 8; ++j) {
        int n = nb + j; n = n < N_NODES ? n : N_NODES - 1;
        vrow[j] = (const float4*)(h + (size_t)n * 128);
    }
    #pragma unroll 4
    for (int kq = 0; kq < 32; ++kq) {
        const int k = kq * 4;
        float4 w0 = *(const float4*)(sW + (k + 0) * 80 + o4);
        float4 w1 = *(const float4*)(sW + (k + 1) * 80 + o4);
        float4 w2 = *(const float4*)(sW + (k + 2) * 80 + o4);
        float4 w3 = *(const float4*)(sW + (k + 3) * 80 + o4);
        #pragma unroll
        for (int j = 0; j < 8; ++j) {
            float4 v = vrow[j][kq];
            acc[j][0] = fmaf(v.x, w0.x, fmaf(v.y, w1.x, fmaf(v.z, w2.x, fmaf(v.w, w3.x, acc[j][0]))));
            acc[j][1] = fmaf(v.x, w0.y, fmaf(v.y, w1.y, fmaf(v.z, w2.y, fmaf(v.w, w3.y, acc[j][1]))));
            acc[j][2] = fmaf(v.x, w0.z, fmaf(v.y, w1.z, fmaf(v.z, w2.z, fmaf(v.w, w3.z, acc[j][2]))));
            acc[j][3] = fmaf(v.x, w0.w, fmaf(v.y, w1.w, fmaf(v.z, w2.w, fmaf(v.w, w3.w, acc[j][3]))));
        }
    }
    #pragma unroll
    for (int j = 0; j < 8; ++j) {
        int n = nb + j;
        if (n < N_NODES) {
            float4 r = make_float4(acc[j][0], acc[j][1], acc[j][2], acc[j][3]);
            if (o4 < 40) *(float4*)(P + (size_t)n * 40 + o4) = r;
            else         *(float4*)(R + (size_t)n * 40 + (o4 - 40)) = r;
        }
    }
}

// final: logits = mean_agg(P[src]) + R; softmax over 40; one wave per node
__global__ __launch_bounds__(256) void k_final(
    const float* __restrict__ P, const float* __restrict__ R,
    const int* __restrict__ rowp, const int* __restrict__ col,
    const float* __restrict__ invd, float* __restrict__ out) {
    int w = blockIdx.x * 4 + (threadIdx.x >> 6);
    if (w >= N_NODES) return;
    int lane = threadIdx.x & 63;
    bool act = lane < 40;
    int beg = rowp[w], end = rowp[w + 1];
    float a0 = 0.f, a1 = 0.f, a2 = 0.f, a3 = 0.f;
    int e = beg;
    for (; e + 4 <= end; e += 4) {
        int s0 = col[e], s1 = col[e + 1], s2 = col[e + 2], s3 = col[e + 3];
        if (act) {
            a0 += P[(size_t)s0 * 40 + lane];
            a1 += P[(size_t)s1 * 40 + lane];
            a2 += P[(size_t)s2 * 40 + lane];
            a3 += P[(size_t)s3 * 40 + lane];
        }
    }
    for (; e < end; ++e) if (act) a0 += P[(size_t)col[e] * 40 + lane];
    float acc = (a0 + a1) + (a2 + a3);
    float v = act ? (acc * invd[w] + R[(size_t)w * 40 + lane]) : -1e30f;
    float m = v;
    #pragma unroll
    for (int off = 32; off; off >>= 1) m = fmaxf(m, __shfl_xor(m, off, 64));
    float ex = act ? expf(v - m) : 0.f;
    float s = ex;
    #pragma unroll
    for (int off = 32; off; off >>= 1) s += __shfl_xor(s, off, 64);
    if (act) out[(size_t)w * 40 + lane] = ex / s;
}

extern "C" void kernel_launch(void* const* d_in, const int* in_sizes, int n_in,
                              void* d_out, int out_size, void* d_ws, size_t ws_size,
                              hipStream_t stream) {
    const float* x   = (const float*)d_in[0];
    const void*  ei  = d_in[1];
    const float* Wl0 = (const float*)d_in[2];
    const float* Wr0 = (const float*)d_in[3];
    const float* b0  = (const float*)d_in[4];
    const float* Wl1 = (const float*)d_in[5];
    const float* Wr1 = (const float*)d_in[6];
    const float* b1  = (const float*)d_in[7];
    const float* Wl2 = (const float*)d_in[8];
    const float* Wr2 = (const float*)d_in[9];
    const float* b2  = (const float*)d_in[10];
    float* out = (float*)d_out;

    char* ws = (char*)d_ws;
    int*   row_ptr = (int*)(ws + WS_ROWPTR);
    int*   deg     = (int*)(ws + WS_DEG);
    int*   fill    = (int*)(ws + WS_FILL);
    float* invd    = (float*)(ws + WS_INVDEG);
    int*   bsum    = (int*)(ws + WS_BSUM);
    int*   flag    = (int*)(ws + WS_FLAG);
    float* WlT0    = (float*)(ws + WS_WLT0);
    float* WrT0    = (float*)(ws + WS_WRT0);
    float* WlT1    = (float*)(ws + WS_WLT1);
    float* WrT1    = (float*)(ws + WS_WRT1);
    float* WcT2    = (float*)(ws + WS_WCT2);
    int*   col     = (int*)(ws + WS_COL);
    float* agg     = (float*)(ws + WS_AGG);
    float* h1      = (float*)(ws + WS_H1);
    float* h2      = (float*)(ws + WS_H2);
    float* P       = (float*)(ws + WS_P);
    float* R       = (float*)(ws + WS_R);

    // zero deg + fill (adjacent)
    hipMemsetAsync(ws + WS_DEG, 0, 800768, stream);

    k_detect<<<1, 256, 0, stream>>>(ei, flag);
    k_transpose<<<64, 256, 0, stream>>>(Wl0, Wr0, Wl1, Wr1, Wl2, Wr2,
                                        WlT0, WrT0, WlT1, WrT1, WcT2);
    k_hist<<<N_EDGES / 256, 256, 0, stream>>>(ei, flag, deg);
    k_scan1<<<98, 256, 0, stream>>>(deg, bsum);
    k_scan2<<<1, 64, 0, stream>>>(bsum, row_ptr, 98);
    k_scan3<<<98, 256, 0, stream>>>(deg, bsum, row_ptr);
    k_invdeg<<<391, 256, 0, stream>>>(row_ptr, invd);
    k_scatter<<<N_EDGES / 256, 256, 0, stream>>>(ei, flag, row_ptr, fill, col);

    // layer 0
    k_aggregate<<<25000, 256, 0, stream>>>(x, row_ptr, col, invd, agg);
    k_gemm_fused<<<782, 512, 0, stream>>>(agg, x, WlT0, WrT0, b0, h1);
    // layer 1
    k_aggregate<<<25000, 256, 0, stream>>>(h1, row_ptr, col, invd, agg);
    k_gemm_fused<<<782, 512, 0, stream>>>(agg, h1, WlT1, WrT1, b1, h2);
    // layer 2 (GEMM first, then aggregate the 40-dim projections)
    k_gemm2<<<782, 320, 0, stream>>>(h2, WcT2, b2, P, R);
    k_final<<<25000, 256, 0, stream>>>(P, R, row_ptr, col, invd, out);
}

// Round 3
// 1020.729 us; speedup vs baseline: 2.7896x; 2.7896x over previous
//
#include <hip/hip_runtime.h>
#include <cstdint>
#include <cstddef>

#define N_NODES 100000
#define N_EDGES 1600000

// ---------------- workspace layout (byte offsets) ----------------
#define WS_ROWPTR   0            // (N+1) int
#define WS_DEG      400384       // N int
#define WS_FILL     800768       // N int
#define WS_INVDEG   1201152      // N float
#define WS_BSUM     1601536      // 98 int
#define WS_FLAG     1602560      // 1 int (1 = edge_index is int64)
#define WS_WLT0     1602816      // 128x128 f (transposed [k][o])
#define WS_WRT0     1668352
#define WS_WLT1     1733888
#define WS_WRT1     1799424
#define WS_WCT2     1864960      // 128x80 f ([k][o], o<40 -> Wl2, o>=40 -> Wr2)
#define WS_COL      1906176      // E int
#define WS_AGG      8306432      // N*128 f
#define WS_H1       59506432     // N*128 f
#define WS_H2       110706432    // N*128 f
#define WS_P        WS_AGG              // overlay (agg dead after layer-1 GEMM)
#define WS_R        (WS_AGG + 16000000) // N*40 f

__device__ __forceinline__ int edge_val(const void* ei, long long idx, int m64) {
    return m64 ? (int)((const long long*)ei)[idx] : ((const int*)ei)[idx];
}

// detect int32 vs int64 edge_index: int64 -> all odd 32-bit words are zero
__global__ void k_detect(const void* __restrict__ ei, int* __restrict__ flag) {
    __shared__ int s_any;
    if (threadIdx.x == 0) s_any = 0;
    __syncthreads();
    const int* p = (const int*)ei;
    int any = 0;
    for (int j = 0; j < 8; ++j) any |= p[2 * (threadIdx.x * 8 + j) + 1];
    if (any) s_any = 1;   // benign race: all writers write 1
    __syncthreads();
    if (threadIdx.x == 0) *flag = (s_any == 0) ? 1 : 0;
}

__global__ void k_transpose(const float* __restrict__ Wl0, const float* __restrict__ Wr0,
                            const float* __restrict__ Wl1, const float* __restrict__ Wr1,
                            const float* __restrict__ Wl2, const float* __restrict__ Wr2,
                            float* __restrict__ T0, float* __restrict__ T1,
                            float* __restrict__ T2, float* __restrict__ T3,
                            float* __restrict__ Tc) {
    int i = blockIdx.x * 256 + threadIdx.x;
    if (i < 16384) {
        int o = i >> 7, k = i & 127;
        int d = k * 128 + o;
        T0[d] = Wl0[i]; T1[d] = Wr0[i]; T2[d] = Wl1[i]; T3[d] = Wr1[i];
    }
    if (i < 10240) {
        int k = i / 80, o = i % 80;
        Tc[i] = (o < 40) ? Wl2[o * 128 + k] : Wr2[(o - 40) * 128 + k];
    }
}

__global__ void k_hist(const void* __restrict__ ei, const int* __restrict__ flag,
                       int* __restrict__ deg) {
    int m = *flag;
    int e = blockIdx.x * blockDim.x + threadIdx.x;
    if (e < N_EDGES) {
        int d = edge_val(ei, (long long)N_EDGES + e, m);
        atomicAdd(&deg[d], 1);
    }
}

__global__ void k_scan1(const int* __restrict__ deg, int* __restrict__ bsum) {
    __shared__ int sd[256];
    int t = threadIdx.x;
    int i0 = blockIdx.x * 1024 + t * 4;
    int s = 0;
    #pragma unroll
    for (int j = 0; j < 4; ++j) if (i0 + j < N_NODES) s += deg[i0 + j];
    sd[t] = s; __syncthreads();
    for (int off = 128; off; off >>= 1) {
        if (t < off) sd[t] += sd[t + off];
        __syncthreads();
    }
    if (t == 0) bsum[blockIdx.x] = sd[0];
}

__global__ void k_scan2(int* __restrict__ bsum, int* __restrict__ row_ptr, int nb) {
    if (threadIdx.x == 0 && blockIdx.x == 0) {
        int run = 0;
        for (int i = 0; i < nb; ++i) { int v = bsum[i]; bsum[i] = run; run += v; }
        row_ptr[N_NODES] = run;
    }
}

__global__ void k_scan3(const int* __restrict__ deg, const int* __restrict__ bsum,
                        int* __restrict__ row_ptr) {
    __shared__ int sd[256];
    int t = threadIdx.x;
    int i0 = blockIdx.x * 1024 + t * 4;
    int v[4]; int s = 0;
    #pragma unroll
    for (int j = 0; j < 4; ++j) { v[j] = (i0 + j < N_NODES) ? deg[i0 + j] : 0; s += v[j]; }
    sd[t] = s; __syncthreads();
    for (int off = 1; off < 256; off <<= 1) {
        int x = 0;
        if (t >= off) x = sd[t - off];
        __syncthreads();
        sd[t] += x;
        __syncthreads();
    }
    int run = bsum[blockIdx.x] + sd[t] - s;   // exclusive prefix for this thread
    #pragma unroll
    for (int j = 0; j < 4; ++j) {
        if (i0 + j < N_NODES) row_ptr[i0 + j] = run;
        run += v[j];
    }
}

__global__ void k_invdeg(const int* __restrict__ row_ptr, float* __restrict__ invd) {
    int i = blockIdx.x * 256 + threadIdx.x;
    if (i < N_NODES) {
        int d = row_ptr[i + 1] - row_ptr[i];
        invd[i] = 1.0f / (float)(d > 1 ? d : 1);
    }
}

__global__ void k_scatter(const void* __restrict__ ei, const int* __restrict__ flag,
                          const int* __restrict__ row_ptr, int* __restrict__ fill,
                          int* __restrict__ col) {
    int m = *flag;
    int e = blockIdx.x * blockDim.x + threadIdx.x;
    if (e < N_EDGES) {
        int s = edge_val(ei, e, m);
        int d = edge_val(ei, (long long)N_EDGES + e, m);
        int pos = row_ptr[d] + atomicAdd(&fill[d], 1);
        col[pos] = s;
    }
}

// mean-aggregate 128-dim rows: one wave per node, float2 per lane, 8 edges in flight
__global__ __launch_bounds__(256) void k_aggregate(
    const float* __restrict__ h, const int* __restrict__ rowp,
    const int* __restrict__ col, const float* __restrict__ invd,
    float* __restrict__ agg) {
    int w = blockIdx.x * 4 + (threadIdx.x >> 6);
    if (w >= N_NODES) return;
    int lane = threadIdx.x & 63;
    const float2* hp = (const float2*)h;
    int beg = rowp[w], end = rowp[w + 1];
    float x = 0.f, y = 0.f;
    int e = beg;
    for (; e + 8 <= end; e += 8) {
        int s0 = col[e], s1 = col[e + 1], s2 = col[e + 2], s3 = col[e + 3];
        int s4 = col[e + 4], s5 = col[e + 5], s6 = col[e + 6], s7 = col[e + 7];
        float2 a = hp[(size_t)s0 * 64 + lane];
        float2 b = hp[(size_t)s1 * 64 + lane];
        float2 c = hp[(size_t)s2 * 64 + lane];
        float2 d = hp[(size_t)s3 * 64 + lane];
        float2 a2 = hp[(size_t)s4 * 64 + lane];
        float2 b2 = hp[(size_t)s5 * 64 + lane];
        float2 c2 = hp[(size_t)s6 * 64 + lane];
        float2 d2 = hp[(size_t)s7 * 64 + lane];
        x += (a.x + b.x) + (c.x + d.x) + (a2.x + b2.x) + (c2.x + d2.x);
        y += (a.y + b.y) + (c.y + d.y) + (a2.y + b2.y) + (c2.y + d2.y);
    }
    for (; e + 4 <= end; e += 4) {
        int s0 = col[e], s1 = col[e + 1], s2 = col[e + 2], s3 = col[e + 3];
        float2 a = hp[(size_t)s0 * 64 + lane];
        float2 b = hp[(size_t)s1 * 64 + lane];
        float2 c = hp[(size_t)s2 * 64 + lane];
        float2 d = hp[(size_t)s3 * 64 + lane];
        x += (a.x + b.x) + (c.x + d.x);
        y += (a.y + b.y) + (c.y + d.y);
    }
    for (; e < end; ++e) {
        float2 a = hp[(size_t)col[e] * 64 + lane];
        x += a.x; y += a.y;
    }
    float id = invd[w];
    ((float2*)agg)[(size_t)w * 64 + lane] = make_float2(x * id, y * id);
}

// fused: out = relu(l2norm(agg@WlT + h@WrT + b)); 64 nodes/block, 256 thr.
// NO LDS: W rows are read coalesced from L1/L2 (all waves sweep the same 64KB
// in the same order), V rows are 32-lane broadcasts. Occupancy is VGPR-bound
// only. Node base is clamped so per-thread addressing is base + imm offsets
// (boundary blocks recompute/overwrite identical values — benign).
__global__ __launch_bounds__(256, 4) void k_gemm_fused(
    const float* __restrict__ agg, const float* __restrict__ hin,
    const float* __restrict__ WlT, const float* __restrict__ WrT,
    const float* __restrict__ bias, float* __restrict__ hout) {
    const int t = threadIdx.x;
    const int o4 = (t & 31) * 4;
    const int ng = t >> 5;                 // 0..7
    int nb = blockIdx.x * 64 + ng * 8;
    if (nb > N_NODES - 8) nb = N_NODES - 8;

    float acc[8][4];
    const float4 bv = *(const float4*)(bias + o4);
    #pragma unroll
    for (int j = 0; j < 8; ++j) { acc[j][0] = bv.x; acc[j][1] = bv.y; acc[j][2] = bv.z; acc[j][3] = bv.w; }

    for (int ph = 0; ph < 2; ++ph) {
        const float4* V  = (const float4*)((ph ? hin : agg) + (size_t)nb * 128);
        const float4* Wp = (const float4*)(ph ? WrT : WlT) + (o4 >> 2);
        #pragma unroll 4
        for (int kq = 0; kq < 32; ++kq) {
            float4 w0 = Wp[(4 * kq + 0) * 32];
            float4 w1 = Wp[(4 * kq + 1) * 32];
            float4 w2 = Wp[(4 * kq + 2) * 32];
            float4 w3 = Wp[(4 * kq + 3) * 32];
            #pragma unroll
            for (int j = 0; j < 8; ++j) {
                float4 v = V[j * 32 + kq];
                acc[j][0] = fmaf(v.x, w0.x, fmaf(v.y, w1.x, fmaf(v.z, w2.x, fmaf(v.w, w3.x, acc[j][0]))));
                acc[j][1] = fmaf(v.x, w0.y, fmaf(v.y, w1.y, fmaf(v.z, w2.y, fmaf(v.w, w3.y, acc[j][1]))));
                acc[j][2] = fmaf(v.x, w0.z, fmaf(v.y, w1.z, fmaf(v.z, w2.z, fmaf(v.w, w3.z, acc[j][2]))));
                acc[j][3] = fmaf(v.x, w0.w, fmaf(v.y, w1.w, fmaf(v.z, w2.w, fmaf(v.w, w3.w, acc[j][3]))));
            }
        }
    }
    // epilogue: L2-normalize over the 128 outs (spread across 32 lanes), relu, store
    #pragma unroll
    for (int j = 0; j < 8; ++j) {
        float ss = acc[j][0] * acc[j][0] + acc[j][1] * acc[j][1]
                 + acc[j][2] * acc[j][2] + acc[j][3] * acc[j][3];
        #pragma unroll
        for (int m = 1; m < 32; m <<= 1) ss += __shfl_xor(ss, m, 64);
        float sc = 1.0f / fmaxf(sqrtf(ss), 1e-12f);
        float4 r = make_float4(fmaxf(acc[j][0] * sc, 0.f), fmaxf(acc[j][1] * sc, 0.f),
                               fmaxf(acc[j][2] * sc, 0.f), fmaxf(acc[j][3] * sc, 0.f));
        *(float4*)(hout + (size_t)(nb + j) * 128 + o4) = r;
    }
}

// layer 2: P = h@Wl2T ; R = h@Wr2T + b2   (80 outs, cat-W in LDS)
__global__ __launch_bounds__(320, 2) void k_gemm2(
    const float* __restrict__ h, const float* __restrict__ WcatT,
    const float* __restrict__ b2, float* __restrict__ P, float* __restrict__ R) {
    __shared__ float sW[128 * 80];
    const int t = threadIdx.x;
    const int o4 = (t % 20) * 4;           // 0..76
    const int ng = t / 20;                 // 0..15
    const int nb = blockIdx.x * 128 + ng * 8;
    #pragma unroll
    for (int j = 0; j < 8; ++j)
        ((float4*)sW)[t + 320 * j] = ((const float4*)WcatT)[t + 320 * j];
    __syncthreads();
    float4 binit = make_float4(0.f, 0.f, 0.f, 0.f);
    if (o4 >= 40) binit = *(const float4*)(b2 + (o4 - 40));
    float acc[8][4];
    #pragma unroll
    for (int j = 0; j < 8; ++j) { acc[j][0] = binit.x; acc[j][1] = binit.y; acc[j][2] = binit.z; acc[j][3] = binit.w; }
    const float4* vrow[8];
    #pragma unroll
    for (int j = 0; j < 8; ++j) {
        int n = nb + j; n = n < N_NODES ? n : N_NODES - 1;
        vrow[j] = (const float4*)(h + (size_t)n * 128);
    }
    #pragma unroll 4
    for (int kq = 0; kq < 32; ++kq) {
        const int k = kq * 4;
        float4 w0 = *(const float4*)(sW + (k + 0) * 80 + o4);
        float4 w1 = *(const float4*)(sW + (k + 1) * 80 + o4);
        float4 w2 = *(const float4*)(sW + (k + 2) * 80 + o4);
        float4 w3 = *(const float4*)(sW + (k + 3) * 80 + o4);
        #pragma unroll
        for (int j = 0; j < 8; ++j) {
            float4 v = vrow[j][kq];
            acc[j][0] = fmaf(v.x, w0.x, fmaf(v.y, w1.x, fmaf(v.z, w2.x, fmaf(v.w, w3.x, acc[j][0]))));
            acc[j][1] = fmaf(v.x, w0.y, fmaf(v.y, w1.y, fmaf(v.z, w2.y, fmaf(v.w, w3.y, acc[j][1]))));
            acc[j][2] = fmaf(v.x, w0.z, fmaf(v.y, w1.z, fmaf(v.z, w2.z, fmaf(v.w, w3.z, acc[j][2]))));
            acc[j][3] = fmaf(v.x, w0.w, fmaf(v.y, w1.w, fmaf(v.z, w2.w, fmaf(v.w, w3.w, acc[j][3]))));
        }
    }
    #pragma unroll
    for (int j = 0; j < 8; ++j) {
        int n = nb + j;
        if (n < N_NODES) {
            float4 r = make_float4(acc[j][0], acc[j][1], acc[j][2], acc[j][3]);
            if (o4 < 40) *(float4*)(P + (size_t)n * 40 + o4) = r;
            else         *(float4*)(R + (size_t)n * 40 + (o4 - 40)) = r;
        }
    }
}

// final: logits = mean_agg(P[src]) + R; softmax over 40; one wave per node
__global__ __launch_bounds__(256) void k_final(
    const float* __restrict__ P, const float* __restrict__ R,
    const int* __restrict__ rowp, const int* __restrict__ col,
    const float* __restrict__ invd, float* __restrict__ out) {
    int w = blockIdx.x * 4 + (threadIdx.x >> 6);
    if (w >= N_NODES) return;
    int lane = threadIdx.x & 63;
    bool act = lane < 40;
    int beg = rowp[w], end = rowp[w + 1];
    float a0 = 0.f, a1 = 0.f, a2 = 0.f, a3 = 0.f;
    int e = beg;
    for (; e + 4 <= end; e += 4) {
        int s0 = col[e], s1 = col[e + 1], s2 = col[e + 2], s3 = col[e + 3];
        if (act) {
            a0 += P[(size_t)s0 * 40 + lane];
            a1 += P[(size_t)s1 * 40 + lane];
            a2 += P[(size_t)s2 * 40 + lane];
            a3 += P[(size_t)s3 * 40 + lane];
        }
    }
    for (; e < end; ++e) if (act) a0 += P[(size_t)col[e] * 40 + lane];
    float acc = (a0 + a1) + (a2 + a3);
    float v = act ? (acc * invd[w] + R[(size_t)w * 40 + lane]) : -1e30f;
    float m = v;
    #pragma unroll
    for (int off = 32; off; off >>= 1) m = fmaxf(m, __shfl_xor(m, off, 64));
    float ex = act ? expf(v - m) : 0.f;
    float s = ex;
    #pragma unroll
    for (int off = 32; off; off >>= 1) s += __shfl_xor(s, off, 64);
    if (act) out[(size_t)w * 40 + lane] = ex / s;
}

extern "C" void kernel_launch(void* const* d_in, const int* in_sizes, int n_in,
                              void* d_out, int out_size, void* d_ws, size_t ws_size,
                              hipStream_t stream) {
    const float* x   = (const float*)d_in[0];
    const void*  ei  = d_in[1];
    const float* Wl0 = (const float*)d_in[2];
    const float* Wr0 = (const float*)d_in[3];
    const float* b0  = (const float*)d_in[4];
    const float* Wl1 = (const float*)d_in[5];
    const float* Wr1 = (const float*)d_in[6];
    const float* b1  = (const float*)d_in[7];
    const float* Wl2 = (const float*)d_in[8];
    const float* Wr2 = (const float*)d_in[9];
    const float* b2  = (const float*)d_in[10];
    float* out = (float*)d_out;

    char* ws = (char*)d_ws;
    int*   row_ptr = (int*)(ws + WS_ROWPTR);
    int*   deg     = (int*)(ws + WS_DEG);
    int*   fill    = (int*)(ws + WS_FILL);
    float* invd    = (float*)(ws + WS_INVDEG);
    int*   bsum    = (int*)(ws + WS_BSUM);
    int*   flag    = (int*)(ws + WS_FLAG);
    float* WlT0    = (float*)(ws + WS_WLT0);
    float* WrT0    = (float*)(ws + WS_WRT0);
    float* WlT1    = (float*)(ws + WS_WLT1);
    float* WrT1    = (float*)(ws + WS_WRT1);
    float* WcT2    = (float*)(ws + WS_WCT2);
    int*   col     = (int*)(ws + WS_COL);
    float* agg     = (float*)(ws + WS_AGG);
    float* h1      = (float*)(ws + WS_H1);
    float* h2      = (float*)(ws + WS_H2);
    float* P       = (float*)(ws + WS_P);
    float* R       = (float*)(ws + WS_R);

    // zero deg + fill (adjacent)
    hipMemsetAsync(ws + WS_DEG, 0, 800768, stream);

    k_detect<<<1, 256, 0, stream>>>(ei, flag);
    k_transpose<<<64, 256, 0, stream>>>(Wl0, Wr0, Wl1, Wr1, Wl2, Wr2,
                                        WlT0, WrT0, WlT1, WrT1, WcT2);
    k_hist<<<N_EDGES / 256, 256, 0, stream>>>(ei, flag, deg);
    k_scan1<<<98, 256, 0, stream>>>(deg, bsum);
    k_scan2<<<1, 64, 0, stream>>>(bsum, row_ptr, 98);
    k_scan3<<<98, 256, 0, stream>>>(deg, bsum, row_ptr);
    k_invdeg<<<391, 256, 0, stream>>>(row_ptr, invd);
    k_scatter<<<N_EDGES / 256, 256, 0, stream>>>(ei, flag, row_ptr, fill, col);

    // layer 0
    k_aggregate<<<25000, 256, 0, stream>>>(x, row_ptr, col, invd, agg);
    k_gemm_fused<<<1563, 256, 0, stream>>>(agg, x, WlT0, WrT0, b0, h1);
    // layer 1
    k_aggregate<<<25000, 256, 0, stream>>>(h1, row_ptr, col, invd, agg);
    k_gemm_fused<<<1563, 256, 0, stream>>>(agg, h1, WlT1, WrT1, b1, h2);
    // layer 2 (GEMM first, then aggregate the 40-dim projections)
    k_gemm2<<<782, 320, 0, stream>>>(h2, WcT2, b2, P, R);
    k_final<<<25000, 256, 0, stream>>>(P, R, row_ptr, col, invd, out);
}

// Round 4
// 928.469 us; speedup vs baseline: 3.0668x; 1.0994x over previous
//
#include <hip/hip_runtime.h>
#include <cstdint>
#include <cstddef>

#define N_NODES 100000
#define N_EDGES 1600000

// ---------------- workspace layout (byte offsets) ----------------
#define WS_ROWPTR   0            // (N+1) int
#define WS_DEG      400384       // N int
#define WS_FILL     800768       // N int
#define WS_INVDEG   1201152      // N float
#define WS_BSUM     1601536      // 98 int
#define WS_FLAG     1602560      // 1 int (1 = edge_index is int64)
#define WS_WLT0     1602816      // 128x128 f (transposed [k][o])
#define WS_WRT0     1668352
#define WS_WLT1     1733888
#define WS_WRT1     1799424
#define WS_WCT2     1864960      // 128x80 f ([k][o], o<40 -> Wl2, o>=40 -> Wr2)
#define WS_COL      1906176      // E int
#define WS_AGG      8306432      // N*128 f
#define WS_H1       59506432     // N*128 f
#define WS_H2       110706432    // N*128 f
#define WS_P        WS_AGG              // overlay (agg dead after layer-1 GEMM)
#define WS_R        (WS_AGG + 16000000) // N*40 f

__device__ __forceinline__ int edge_val(const void* ei, long long idx, int m64) {
    return m64 ? (int)((const long long*)ei)[idx] : ((const int*)ei)[idx];
}

// detect int32 vs int64 edge_index: int64 -> all odd 32-bit words are zero
__global__ void k_detect(const void* __restrict__ ei, int* __restrict__ flag) {
    __shared__ int s_any;
    if (threadIdx.x == 0) s_any = 0;
    __syncthreads();
    const int* p = (const int*)ei;
    int any = 0;
    for (int j = 0; j < 8; ++j) any |= p[2 * (threadIdx.x * 8 + j) + 1];
    if (any) s_any = 1;   // benign race: all writers write 1
    __syncthreads();
    if (threadIdx.x == 0) *flag = (s_any == 0) ? 1 : 0;
}

__global__ void k_transpose(const float* __restrict__ Wl0, const float* __restrict__ Wr0,
                            const float* __restrict__ Wl1, const float* __restrict__ Wr1,
                            const float* __restrict__ Wl2, const float* __restrict__ Wr2,
                            float* __restrict__ T0, float* __restrict__ T1,
                            float* __restrict__ T2, float* __restrict__ T3,
                            float* __restrict__ Tc) {
    int i = blockIdx.x * 256 + threadIdx.x;
    if (i < 16384) {
        int o = i >> 7, k = i & 127;
        int d = k * 128 + o;
        T0[d] = Wl0[i]; T1[d] = Wr0[i]; T2[d] = Wl1[i]; T3[d] = Wr1[i];
    }
    if (i < 10240) {
        int k = i / 80, o = i % 80;
        Tc[i] = (o < 40) ? Wl2[o * 128 + k] : Wr2[(o - 40) * 128 + k];
    }
}

__global__ void k_hist(const void* __restrict__ ei, const int* __restrict__ flag,
                       int* __restrict__ deg) {
    int m = *flag;
    int e = blockIdx.x * blockDim.x + threadIdx.x;
    if (e < N_EDGES) {
        int d = edge_val(ei, (long long)N_EDGES + e, m);
        atomicAdd(&deg[d], 1);
    }
}

__global__ void k_scan1(const int* __restrict__ deg, int* __restrict__ bsum) {
    __shared__ int sd[256];
    int t = threadIdx.x;
    int i0 = blockIdx.x * 1024 + t * 4;
    int s = 0;
    #pragma unroll
    for (int j = 0; j < 4; ++j) if (i0 + j < N_NODES) s += deg[i0 + j];
    sd[t] = s; __syncthreads();
    for (int off = 128; off; off >>= 1) {
        if (t < off) sd[t] += sd[t + off];
        __syncthreads();
    }
    if (t == 0) bsum[blockIdx.x] = sd[0];
}

__global__ void k_scan2(int* __restrict__ bsum, int* __restrict__ row_ptr, int nb) {
    if (threadIdx.x == 0 && blockIdx.x == 0) {
        int run = 0;
        for (int i = 0; i < nb; ++i) { int v = bsum[i]; bsum[i] = run; run += v; }
        row_ptr[N_NODES] = run;
    }
}

__global__ void k_scan3(const int* __restrict__ deg, const int* __restrict__ bsum,
                        int* __restrict__ row_ptr) {
    __shared__ int sd[256];
    int t = threadIdx.x;
    int i0 = blockIdx.x * 1024 + t * 4;
    int v[4]; int s = 0;
    #pragma unroll
    for (int j = 0; j < 4; ++j) { v[j] = (i0 + j < N_NODES) ? deg[i0 + j] : 0; s += v[j]; }
    sd[t] = s; __syncthreads();
    for (int off = 1; off < 256; off <<= 1) {
        int x = 0;
        if (t >= off) x = sd[t - off];
        __syncthreads();
        sd[t] += x;
        __syncthreads();
    }
    int run = bsum[blockIdx.x] + sd[t] - s;   // exclusive prefix for this thread
    #pragma unroll
    for (int j = 0; j < 4; ++j) {
        if (i0 + j < N_NODES) row_ptr[i0 + j] = run;
        run += v[j];
    }
}

__global__ void k_invdeg(const int* __restrict__ row_ptr, float* __restrict__ invd) {
    int i = blockIdx.x * 256 + threadIdx.x;
    if (i < N_NODES) {
        int d = row_ptr[i + 1] - row_ptr[i];
        invd[i] = 1.0f / (float)(d > 1 ? d : 1);
    }
}

__global__ void k_scatter(const void* __restrict__ ei, const int* __restrict__ flag,
                          const int* __restrict__ row_ptr, int* __restrict__ fill,
                          int* __restrict__ col) {
    int m = *flag;
    int e = blockIdx.x * blockDim.x + threadIdx.x;
    if (e < N_EDGES) {
        int s = edge_val(ei, e, m);
        int d = edge_val(ei, (long long)N_EDGES + e, m);
        int pos = row_ptr[d] + atomicAdd(&fill[d], 1);
        col[pos] = s;
    }
}

// mean-aggregate 128-dim rows: one wave per node, float2 per lane, 8 edges in flight
__global__ __launch_bounds__(256) void k_aggregate(
    const float* __restrict__ h, const int* __restrict__ rowp,
    const int* __restrict__ col, const float* __restrict__ invd,
    float* __restrict__ agg) {
    int w = blockIdx.x * 4 + (threadIdx.x >> 6);
    if (w >= N_NODES) return;
    int lane = threadIdx.x & 63;
    const float2* hp = (const float2*)h;
    int beg = rowp[w], end = rowp[w + 1];
    float x = 0.f, y = 0.f;
    int e = beg;
    for (; e + 8 <= end; e += 8) {
        int s0 = col[e], s1 = col[e + 1], s2 = col[e + 2], s3 = col[e + 3];
        int s4 = col[e + 4], s5 = col[e + 5], s6 = col[e + 6], s7 = col[e + 7];
        float2 a = hp[(size_t)s0 * 64 + lane];
        float2 b = hp[(size_t)s1 * 64 + lane];
        float2 c = hp[(size_t)s2 * 64 + lane];
        float2 d = hp[(size_t)s3 * 64 + lane];
        float2 a2 = hp[(size_t)s4 * 64 + lane];
        float2 b2 = hp[(size_t)s5 * 64 + lane];
        float2 c2 = hp[(size_t)s6 * 64 + lane];
        float2 d2 = hp[(size_t)s7 * 64 + lane];
        x += (a.x + b.x) + (c.x + d.x) + (a2.x + b2.x) + (c2.x + d2.x);
        y += (a.y + b.y) + (c.y + d.y) + (a2.y + b2.y) + (c2.y + d2.y);
    }
    for (; e + 4 <= end; e += 4) {
        int s0 = col[e], s1 = col[e + 1], s2 = col[e + 2], s3 = col[e + 3];
        float2 a = hp[(size_t)s0 * 64 + lane];
        float2 b = hp[(size_t)s1 * 64 + lane];
        float2 c = hp[(size_t)s2 * 64 + lane];
        float2 d = hp[(size_t)s3 * 64 + lane];
        x += (a.x + b.x) + (c.x + d.x);
        y += (a.y + b.y) + (c.y + d.y);
    }
    for (; e < end; ++e) {
        float2 a = hp[(size_t)col[e] * 64 + lane];
        x += a.x; y += a.y;
    }
    float id = invd[w];
    ((float2*)agg)[(size_t)w * 64 + lane] = make_float2(x * id, y * id);
}

// fused: out = relu(l2norm(agg@WlT + h@WrT + b)); 128 nodes/block, 512 thr.
// W staged through 32KB LDS in K=64 chunks (LDS cap: 5 blk/CU); clamped node
// base keeps VGPR ~64 (launch_bounds min-waves=4 -> 128 VGPR cap, NO spill —
// R2's forced ,8 capped VGPR at 32 and spilled 1.9GB to scratch).
__global__ __launch_bounds__(512, 4) void k_gemm_fused(
    const float* __restrict__ agg, const float* __restrict__ hin,
    const float* __restrict__ WlT, const float* __restrict__ WrT,
    const float* __restrict__ bias, float* __restrict__ hout) {
    __shared__ float sW[64 * 128];   // 32 KB
    const int t = threadIdx.x;
    const int o4 = (t & 31) * 4;
    const int ng = t >> 5;                 // 0..15
    int nb = blockIdx.x * 128 + ng * 8;
    if (nb > N_NODES - 8) nb = N_NODES - 8;

    float acc[8][4];
    const float4 bv = *(const float4*)(bias + o4);
    #pragma unroll
    for (int j = 0; j < 8; ++j) { acc[j][0] = bv.x; acc[j][1] = bv.y; acc[j][2] = bv.z; acc[j][3] = bv.w; }

    for (int ph = 0; ph < 2; ++ph) {
        const float4* V  = (const float4*)((ph ? hin : agg) + (size_t)nb * 128);
        const float*  WT = ph ? WrT : WlT;
        for (int kh = 0; kh < 2; ++kh) {
            __syncthreads();
            const float4* wsrc = (const float4*)(WT + kh * 64 * 128);
            #pragma unroll
            for (int j = 0; j < 4; ++j)
                ((float4*)sW)[t + 512 * j] = wsrc[t + 512 * j];
            __syncthreads();
            #pragma unroll 4
            for (int kq = 0; kq < 16; ++kq) {
                const int k = kq * 4;
                float4 w0 = *(const float4*)(sW + (k + 0) * 128 + o4);
                float4 w1 = *(const float4*)(sW + (k + 1) * 128 + o4);
                float4 w2 = *(const float4*)(sW + (k + 2) * 128 + o4);
                float4 w3 = *(const float4*)(sW + (k + 3) * 128 + o4);
                #pragma unroll
                for (int j = 0; j < 8; ++j) {
                    float4 v = V[j * 32 + kh * 16 + kq];
                    acc[j][0] = fmaf(v.x, w0.x, fmaf(v.y, w1.x, fmaf(v.z, w2.x, fmaf(v.w, w3.x, acc[j][0]))));
                    acc[j][1] = fmaf(v.x, w0.y, fmaf(v.y, w1.y, fmaf(v.z, w2.y, fmaf(v.w, w3.y, acc[j][1]))));
                    acc[j][2] = fmaf(v.x, w0.z, fmaf(v.y, w1.z, fmaf(v.z, w2.z, fmaf(v.w, w3.z, acc[j][2]))));
                    acc[j][3] = fmaf(v.x, w0.w, fmaf(v.y, w1.w, fmaf(v.z, w2.w, fmaf(v.w, w3.w, acc[j][3]))));
                }
            }
        }
    }
    // epilogue: L2-normalize over the 128 outs (spread across 32 lanes), relu, store
    #pragma unroll
    for (int j = 0; j < 8; ++j) {
        float ss = acc[j][0] * acc[j][0] + acc[j][1] * acc[j][1]
                 + acc[j][2] * acc[j][2] + acc[j][3] * acc[j][3];
        #pragma unroll
        for (int m = 1; m < 32; m <<= 1) ss += __shfl_xor(ss, m, 64);
        float sc = 1.0f / fmaxf(sqrtf(ss), 1e-12f);
        float4 r = make_float4(fmaxf(acc[j][0] * sc, 0.f), fmaxf(acc[j][1] * sc, 0.f),
                               fmaxf(acc[j][2] * sc, 0.f), fmaxf(acc[j][3] * sc, 0.f));
        *(float4*)(hout + (size_t)(nb + j) * 128 + o4) = r;
    }
}

// layer 2: P = h@Wl2T ; R = h@Wr2T + b2   (80 outs, cat-W in LDS)
__global__ __launch_bounds__(320, 2) void k_gemm2(
    const float* __restrict__ h, const float* __restrict__ WcatT,
    const float* __restrict__ b2, float* __restrict__ P, float* __restrict__ R) {
    __shared__ float sW[128 * 80];
    const int t = threadIdx.x;
    const int o4 = (t % 20) * 4;           // 0..76
    const int ng = t / 20;                 // 0..15
    const int nb = blockIdx.x * 128 + ng * 8;
    #pragma unroll
    for (int j = 0; j < 8; ++j)
        ((float4*)sW)[t + 320 * j] = ((const float4*)WcatT)[t + 320 * j];
    __syncthreads();
    float4 binit = make_float4(0.f, 0.f, 0.f, 0.f);
    if (o4 >= 40) binit = *(const float4*)(b2 + (o4 - 40));
    float acc[8][4];
    #pragma unroll
    for (int j = 0; j < 8; ++j) { acc[j][0] = binit.x; acc[j][1] = binit.y; acc[j][2] = binit.z; acc[j][3] = binit.w; }
    const float4* vrow[8];
    #pragma unroll
    for (int j = 0; j < 8; ++j) {
        int n = nb + j; n = n < N_NODES ? n : N_NODES - 1;
        vrow[j] = (const float4*)(h + (size_t)n * 128);
    }
    #pragma unroll 4
    for (int kq = 0; kq < 32; ++kq) {
        const int k = kq * 4;
        float4 w0 = *(const float4*)(sW + (k + 0) * 80 + o4);
        float4 w1 = *(const float4*)(sW + (k + 1) * 80 + o4);
        float4 w2 = *(const float4*)(sW + (k + 2) * 80 + o4);
        float4 w3 = *(const float4*)(sW + (k + 3) * 80 + o4);
        #pragma unroll
        for (int j = 0; j < 8; ++j) {
            float4 v = vrow[j][kq];
            acc[j][0] = fmaf(v.x, w0.x, fmaf(v.y, w1.x, fmaf(v.z, w2.x, fmaf(v.w, w3.x, acc[j][0]))));
            acc[j][1] = fmaf(v.x, w0.y, fmaf(v.y, w1.y, fmaf(v.z, w2.y, fmaf(v.w, w3.y, acc[j][1]))));
            acc[j][2] = fmaf(v.x, w0.z, fmaf(v.y, w1.z, fmaf(v.z, w2.z, fmaf(v.w, w3.z, acc[j][2]))));
            acc[j][3] = fmaf(v.x, w0.w, fmaf(v.y, w1.w, fmaf(v.z, w2.w, fmaf(v.w, w3.w, acc[j][3]))));
        }
    }
    #pragma unroll
    for (int j = 0; j < 8; ++j) {
        int n = nb + j;
        if (n < N_NODES) {
            float4 r = make_float4(acc[j][0], acc[j][1], acc[j][2], acc[j][3]);
            if (o4 < 40) *(float4*)(P + (size_t)n * 40 + o4) = r;
            else         *(float4*)(R + (size_t)n * 40 + (o4 - 40)) = r;
        }
    }
}

// final: logits = mean_agg(P[src]) + R; softmax over 40; one wave per node
__global__ __launch_bounds__(256) void k_final(
    const float* __restrict__ P, const float* __restrict__ R,
    const int* __restrict__ rowp, const int* __restrict__ col,
    const float* __restrict__ invd, float* __restrict__ out) {
    int w = blockIdx.x * 4 + (threadIdx.x >> 6);
    if (w >= N_NODES) return;
    int lane = threadIdx.x & 63;
    bool act = lane < 40;
    int beg = rowp[w], end = rowp[w + 1];
    float a0 = 0.f, a1 = 0.f, a2 = 0.f, a3 = 0.f;
    int e = beg;
    for (; e + 4 <= end; e += 4) {
        int s0 = col[e], s1 = col[e + 1], s2 = col[e + 2], s3 = col[e + 3];
        if (act) {
            a0 += P[(size_t)s0 * 40 + lane];
            a1 += P[(size_t)s1 * 40 + lane];
            a2 += P[(size_t)s2 * 40 + lane];
            a3 += P[(size_t)s3 * 40 + lane];
        }
    }
    for (; e < end; ++e) if (act) a0 += P[(size_t)col[e] * 40 + lane];
    float acc = (a0 + a1) + (a2 + a3);
    float v = act ? (acc * invd[w] + R[(size_t)w * 40 + lane]) : -1e30f;
    float m = v;
    #pragma unroll
    for (int off = 32; off; off >>= 1) m = fmaxf(m, __shfl_xor(m, off, 64));
    float ex = act ? expf(v - m) : 0.f;
    float s = ex;
    #pragma unroll
    for (int off = 32; off; off >>= 1) s += __shfl_xor(s, off, 64);
    if (act) out[(size_t)w * 40 + lane] = ex / s;
}

extern "C" void kernel_launch(void* const* d_in, const int* in_sizes, int n_in,
                              void* d_out, int out_size, void* d_ws, size_t ws_size,
                              hipStream_t stream) {
    const float* x   = (const float*)d_in[0];
    const void*  ei  = d_in[1];
    const float* Wl0 = (const float*)d_in[2];
    const float* Wr0 = (const float*)d_in[3];
    const float* b0  = (const float*)d_in[4];
    const float* Wl1 = (const float*)d_in[5];
    const float* Wr1 = (const float*)d_in[6];
    const float* b1  = (const float*)d_in[7];
    const float* Wl2 = (const float*)d_in[8];
    const float* Wr2 = (const float*)d_in[9];
    const float* b2  = (const float*)d_in[10];
    float* out = (float*)d_out;

    char* ws = (char*)d_ws;
    int*   row_ptr = (int*)(ws + WS_ROWPTR);
    int*   deg     = (int*)(ws + WS_DEG);
    int*   fill    = (int*)(ws + WS_FILL);
    float* invd    = (float*)(ws + WS_INVDEG);
    int*   bsum    = (int*)(ws + WS_BSUM);
    int*   flag    = (int*)(ws + WS_FLAG);
    float* WlT0    = (float*)(ws + WS_WLT0);
    float* WrT0    = (float*)(ws + WS_WRT0);
    float* WlT1    = (float*)(ws + WS_WLT1);
    float* WrT1    = (float*)(ws + WS_WRT1);
    float* WcT2    = (float*)(ws + WS_WCT2);
    int*   col     = (int*)(ws + WS_COL);
    float* agg     = (float*)(ws + WS_AGG);
    float* h1      = (float*)(ws + WS_H1);
    float* h2      = (float*)(ws + WS_H2);
    float* P       = (float*)(ws + WS_P);
    float* R       = (float*)(ws + WS_R);

    // zero deg + fill (adjacent)
    hipMemsetAsync(ws + WS_DEG, 0, 800768, stream);

    k_detect<<<1, 256, 0, stream>>>(ei, flag);
    k_transpose<<<64, 256, 0, stream>>>(Wl0, Wr0, Wl1, Wr1, Wl2, Wr2,
                                        WlT0, WrT0, WlT1, WrT1, WcT2);
    k_hist<<<N_EDGES / 256, 256, 0, stream>>>(ei, flag, deg);
    k_scan1<<<98, 256, 0, stream>>>(deg, bsum);
    k_scan2<<<1, 64, 0, stream>>>(bsum, row_ptr, 98);
    k_scan3<<<98, 256, 0, stream>>>(deg, bsum, row_ptr);
    k_invdeg<<<391, 256, 0, stream>>>(row_ptr, invd);
    k_scatter<<<N_EDGES / 256, 256, 0, stream>>>(ei, flag, row_ptr, fill, col);

    // layer 0
    k_aggregate<<<25000, 256, 0, stream>>>(x, row_ptr, col, invd, agg);
    k_gemm_fused<<<782, 512, 0, stream>>>(agg, x, WlT0, WrT0, b0, h1);
    // layer 1
    k_aggregate<<<25000, 256, 0, stream>>>(h1, row_ptr, col, invd, agg);
    k_gemm_fused<<<782, 512, 0, stream>>>(agg, h1, WlT1, WrT1, b1, h2);
    // layer 2 (GEMM first, then aggregate the 40-dim projections)
    k_gemm2<<<782, 320, 0, stream>>>(h2, WcT2, b2, P, R);
    k_final<<<25000, 256, 0, stream>>>(P, R, row_ptr, col, invd, out);
}

// Round 5
// 904.490 us; speedup vs baseline: 3.1481x; 1.0265x over previous
//
#include <hip/hip_runtime.h>
#include <cstdint>
#include <cstddef>

#define N_NODES 100000
#define N_EDGES 1600000

// ---------------- workspace layout (byte offsets) ----------------
#define WS_ROWPTR   0            // (N+1) int
#define WS_DEG      400384       // N int
#define WS_FILL     800768       // N int
#define WS_INVDEG   1201152      // N float
#define WS_BSUM     1601536      // 98 int
#define WS_FLAG     1602560      // 1 int (1 = edge_index is int64)
#define WS_WLT0     1602816      // 128x128 f (transposed [k][o])
#define WS_WRT0     1668352
#define WS_WLT1     1733888
#define WS_WRT1     1799424
#define WS_WCT2     1864960      // 128x80 f ([k][o], o<40 -> Wl2, o>=40 -> Wr2)
#define WS_COL      1906176      // E int
#define WS_AGG      8306432      // N*128 f
#define WS_H1       59506432     // N*128 f
#define WS_H2       110706432    // N*128 f
#define WS_P        WS_AGG              // overlay (agg dead after layer-1 GEMM)
#define WS_R        (WS_AGG + 16000000) // N*40 f

__device__ __forceinline__ int edge_val(const void* ei, long long idx, int m64) {
    return m64 ? (int)((const long long*)ei)[idx] : ((const int*)ei)[idx];
}

// detect int32 vs int64 edge_index: int64 -> all odd 32-bit words are zero
__global__ void k_detect(const void* __restrict__ ei, int* __restrict__ flag) {
    __shared__ int s_any;
    if (threadIdx.x == 0) s_any = 0;
    __syncthreads();
    const int* p = (const int*)ei;
    int any = 0;
    for (int j = 0; j < 8; ++j) any |= p[2 * (threadIdx.x * 8 + j) + 1];
    if (any) s_any = 1;   // benign race: all writers write 1
    __syncthreads();
    if (threadIdx.x == 0) *flag = (s_any == 0) ? 1 : 0;
}

__global__ void k_transpose(const float* __restrict__ Wl0, const float* __restrict__ Wr0,
                            const float* __restrict__ Wl1, const float* __restrict__ Wr1,
                            const float* __restrict__ Wl2, const float* __restrict__ Wr2,
                            float* __restrict__ T0, float* __restrict__ T1,
                            float* __restrict__ T2, float* __restrict__ T3,
                            float* __restrict__ Tc) {
    int i = blockIdx.x * 256 + threadIdx.x;
    if (i < 16384) {
        int o = i >> 7, k = i & 127;
        int d = k * 128 + o;
        T0[d] = Wl0[i]; T1[d] = Wr0[i]; T2[d] = Wl1[i]; T3[d] = Wr1[i];
    }
    if (i < 10240) {
        int k = i / 80, o = i % 80;
        Tc[i] = (o < 40) ? Wl2[o * 128 + k] : Wr2[(o - 40) * 128 + k];
    }
}

__global__ void k_hist(const void* __restrict__ ei, const int* __restrict__ flag,
                       int* __restrict__ deg) {
    int m = *flag;
    int e = blockIdx.x * blockDim.x + threadIdx.x;
    if (e < N_EDGES) {
        int d = edge_val(ei, (long long)N_EDGES + e, m);
        atomicAdd(&deg[d], 1);
    }
}

__global__ void k_scan1(const int* __restrict__ deg, int* __restrict__ bsum) {
    __shared__ int sd[256];
    int t = threadIdx.x;
    int i0 = blockIdx.x * 1024 + t * 4;
    int s = 0;
    #pragma unroll
    for (int j = 0; j < 4; ++j) if (i0 + j < N_NODES) s += deg[i0 + j];
    sd[t] = s; __syncthreads();
    for (int off = 128; off; off >>= 1) {
        if (t < off) sd[t] += sd[t + off];
        __syncthreads();
    }
    if (t == 0) bsum[blockIdx.x] = sd[0];
}

__global__ void k_scan2(int* __restrict__ bsum, int* __restrict__ row_ptr, int nb) {
    if (threadIdx.x == 0 && blockIdx.x == 0) {
        int run = 0;
        for (int i = 0; i < nb; ++i) { int v = bsum[i]; bsum[i] = run; run += v; }
        row_ptr[N_NODES] = run;
    }
}

__global__ void k_scan3(const int* __restrict__ deg, const int* __restrict__ bsum,
                        int* __restrict__ row_ptr) {
    __shared__ int sd[256];
    int t = threadIdx.x;
    int i0 = blockIdx.x * 1024 + t * 4;
    int v[4]; int s = 0;
    #pragma unroll
    for (int j = 0; j < 4; ++j) { v[j] = (i0 + j < N_NODES) ? deg[i0 + j] : 0; s += v[j]; }
    sd[t] = s; __syncthreads();
    for (int off = 1; off < 256; off <<= 1) {
        int x = 0;
        if (t >= off) x = sd[t - off];
        __syncthreads();
        sd[t] += x;
        __syncthreads();
    }
    int run = bsum[blockIdx.x] + sd[t] - s;   // exclusive prefix for this thread
    #pragma unroll
    for (int j = 0; j < 4; ++j) {
        if (i0 + j < N_NODES) row_ptr[i0 + j] = run;
        run += v[j];
    }
}

__global__ void k_invdeg(const int* __restrict__ row_ptr, float* __restrict__ invd) {
    int i = blockIdx.x * 256 + threadIdx.x;
    if (i < N_NODES) {
        int d = row_ptr[i + 1] - row_ptr[i];
        invd[i] = 1.0f / (float)(d > 1 ? d : 1);
    }
}

__global__ void k_scatter(const void* __restrict__ ei, const int* __restrict__ flag,
                          const int* __restrict__ row_ptr, int* __restrict__ fill,
                          int* __restrict__ col) {
    int m = *flag;
    int e = blockIdx.x * blockDim.x + threadIdx.x;
    if (e < N_EDGES) {
        int s = edge_val(ei, e, m);
        int d = edge_val(ei, (long long)N_EDGES + e, m);
        int pos = row_ptr[d] + atomicAdd(&fill[d], 1);
        col[pos] = s;
    }
}

// mean-aggregate 128-dim rows: one wave per node, float2 per lane, 8 edges in flight
__global__ __launch_bounds__(256) void k_aggregate(
    const float* __restrict__ h, const int* __restrict__ rowp,
    const int* __restrict__ col, const float* __restrict__ invd,
    float* __restrict__ agg) {
    int w = blockIdx.x * 4 + (threadIdx.x >> 6);
    if (w >= N_NODES) return;
    int lane = threadIdx.x & 63;
    const float2* hp = (const float2*)h;
    int beg = rowp[w], end = rowp[w + 1];
    float x = 0.f, y = 0.f;
    int e = beg;
    for (; e + 8 <= end; e += 8) {
        int s0 = col[e], s1 = col[e + 1], s2 = col[e + 2], s3 = col[e + 3];
        int s4 = col[e + 4], s5 = col[e + 5], s6 = col[e + 6], s7 = col[e + 7];
        float2 a = hp[(size_t)s0 * 64 + lane];
        float2 b = hp[(size_t)s1 * 64 + lane];
        float2 c = hp[(size_t)s2 * 64 + lane];
        float2 d = hp[(size_t)s3 * 64 + lane];
        float2 a2 = hp[(size_t)s4 * 64 + lane];
        float2 b2 = hp[(size_t)s5 * 64 + lane];
        float2 c2 = hp[(size_t)s6 * 64 + lane];
        float2 d2 = hp[(size_t)s7 * 64 + lane];
        x += (a.x + b.x) + (c.x + d.x) + (a2.x + b2.x) + (c2.x + d2.x);
        y += (a.y + b.y) + (c.y + d.y) + (a2.y + b2.y) + (c2.y + d2.y);
    }
    for (; e + 4 <= end; e += 4) {
        int s0 = col[e], s1 = col[e + 1], s2 = col[e + 2], s3 = col[e + 3];
        float2 a = hp[(size_t)s0 * 64 + lane];
        float2 b = hp[(size_t)s1 * 64 + lane];
        float2 c = hp[(size_t)s2 * 64 + lane];
        float2 d = hp[(size_t)s3 * 64 + lane];
        x += (a.x + b.x) + (c.x + d.x);
        y += (a.y + b.y) + (c.y + d.y);
    }
    for (; e < end; ++e) {
        float2 a = hp[(size_t)col[e] * 64 + lane];
        x += a.x; y += a.y;
    }
    float id = invd[w];
    ((float2*)agg)[(size_t)w * 64 + lane] = make_float2(x * id, y * id);
}

// fused: out = relu(l2norm(agg@WlT + h@WrT + b)); 64 nodes/block, 256 thr.
// W staged through 16KB LDS chunks (K=32, 4 chunks/phase). Small blocks ->
// grid 1563 ~= 6 blocks/CU all co-resident; a barrier stalls only 4 waves
// while ~20 other waves keep issuing (R4's 512-thr blocks at 3/CU stalled
// 1/3 of the CU per barrier -> VALUBusy 35%).
__global__ __launch_bounds__(256, 4) void k_gemm_fused(
    const float* __restrict__ agg, const float* __restrict__ hin,
    const float* __restrict__ WlT, const float* __restrict__ WrT,
    const float* __restrict__ bias, float* __restrict__ hout) {
    __shared__ float sW[32 * 128];   // 16 KB
    const int t = threadIdx.x;
    const int o4 = (t & 31) * 4;
    const int ng = t >> 5;                 // 0..7
    int nb = blockIdx.x * 64 + ng * 8;
    if (nb > N_NODES - 8) nb = N_NODES - 8;   // tail blocks recompute identical rows — benign

    float acc[8][4];
    const float4 bv = *(const float4*)(bias + o4);
    #pragma unroll
    for (int j = 0; j < 8; ++j) { acc[j][0] = bv.x; acc[j][1] = bv.y; acc[j][2] = bv.z; acc[j][3] = bv.w; }

    for (int ph = 0; ph < 2; ++ph) {
        const float4* V  = (const float4*)((ph ? hin : agg) + (size_t)nb * 128);
        const float*  WT = ph ? WrT : WlT;
        for (int kc = 0; kc < 4; ++kc) {
            __syncthreads();
            const float4* wsrc = (const float4*)(WT + kc * 32 * 128);
            #pragma unroll
            for (int j = 0; j < 4; ++j)
                ((float4*)sW)[t + 256 * j] = wsrc[t + 256 * j];
            __syncthreads();
            #pragma unroll
            for (int kq = 0; kq < 8; ++kq) {
                const int k = kq * 4;
                float4 w0 = *(const float4*)(sW + (k + 0) * 128 + o4);
                float4 w1 = *(const float4*)(sW + (k + 1) * 128 + o4);
                float4 w2 = *(const float4*)(sW + (k + 2) * 128 + o4);
                float4 w3 = *(const float4*)(sW + (k + 3) * 128 + o4);
                #pragma unroll
                for (int j = 0; j < 8; ++j) {
                    float4 v = V[j * 32 + kc * 8 + kq];
                    acc[j][0] = fmaf(v.x, w0.x, fmaf(v.y, w1.x, fmaf(v.z, w2.x, fmaf(v.w, w3.x, acc[j][0]))));
                    acc[j][1] = fmaf(v.x, w0.y, fmaf(v.y, w1.y, fmaf(v.z, w2.y, fmaf(v.w, w3.y, acc[j][1]))));
                    acc[j][2] = fmaf(v.x, w0.z, fmaf(v.y, w1.z, fmaf(v.z, w2.z, fmaf(v.w, w3.z, acc[j][2]))));
                    acc[j][3] = fmaf(v.x, w0.w, fmaf(v.y, w1.w, fmaf(v.z, w2.w, fmaf(v.w, w3.w, acc[j][3]))));
                }
            }
        }
    }
    // epilogue: L2-normalize over the 128 outs (spread across 32 lanes), relu, store
    #pragma unroll
    for (int j = 0; j < 8; ++j) {
        float ss = acc[j][0] * acc[j][0] + acc[j][1] * acc[j][1]
                 + acc[j][2] * acc[j][2] + acc[j][3] * acc[j][3];
        #pragma unroll
        for (int m = 1; m < 32; m <<= 1) ss += __shfl_xor(ss, m, 64);
        float sc = 1.0f / fmaxf(sqrtf(ss), 1e-12f);
        float4 r = make_float4(fmaxf(acc[j][0] * sc, 0.f), fmaxf(acc[j][1] * sc, 0.f),
                               fmaxf(acc[j][2] * sc, 0.f), fmaxf(acc[j][3] * sc, 0.f));
        *(float4*)(hout + (size_t)(nb + j) * 128 + o4) = r;
    }
}

// layer 2: P = h@Wl2T ; R = h@Wr2T + b2   (80 outs, cat-W in LDS)
__global__ __launch_bounds__(320, 2) void k_gemm2(
    const float* __restrict__ h, const float* __restrict__ WcatT,
    const float* __restrict__ b2, float* __restrict__ P, float* __restrict__ R) {
    __shared__ float sW[128 * 80];
    const int t = threadIdx.x;
    const int o4 = (t % 20) * 4;           // 0..76
    const int ng = t / 20;                 // 0..15
    const int nb = blockIdx.x * 128 + ng * 8;
    #pragma unroll
    for (int j = 0; j < 8; ++j)
        ((float4*)sW)[t + 320 * j] = ((const float4*)WcatT)[t + 320 * j];
    __syncthreads();
    float4 binit = make_float4(0.f, 0.f, 0.f, 0.f);
    if (o4 >= 40) binit = *(const float4*)(b2 + (o4 - 40));
    float acc[8][4];
    #pragma unroll
    for (int j = 0; j < 8; ++j) { acc[j][0] = binit.x; acc[j][1] = binit.y; acc[j][2] = binit.z; acc[j][3] = binit.w; }
    const float4* vrow[8];
    #pragma unroll
    for (int j = 0; j < 8; ++j) {
        int n = nb + j; n = n < N_NODES ? n : N_NODES - 1;
        vrow[j] = (const float4*)(h + (size_t)n * 128);
    }
    #pragma unroll 4
    for (int kq = 0; kq < 32; ++kq) {
        const int k = kq * 4;
        float4 w0 = *(const float4*)(sW + (k + 0) * 80 + o4);
        float4 w1 = *(const float4*)(sW + (k + 1) * 80 + o4);
        float4 w2 = *(const float4*)(sW + (k + 2) * 80 + o4);
        float4 w3 = *(const float4*)(sW + (k + 3) * 80 + o4);
        #pragma unroll
        for (int j = 0; j < 8; ++j) {
            float4 v = vrow[j][kq];
            acc[j][0] = fmaf(v.x, w0.x, fmaf(v.y, w1.x, fmaf(v.z, w2.x, fmaf(v.w, w3.x, acc[j][0]))));
            acc[j][1] = fmaf(v.x, w0.y, fmaf(v.y, w1.y, fmaf(v.z, w2.y, fmaf(v.w, w3.y, acc[j][1]))));
            acc[j][2] = fmaf(v.x, w0.z, fmaf(v.y, w1.z, fmaf(v.z, w2.z, fmaf(v.w, w3.z, acc[j][2]))));
            acc[j][3] = fmaf(v.x, w0.w, fmaf(v.y, w1.w, fmaf(v.z, w2.w, fmaf(v.w, w3.w, acc[j][3]))));
        }
    }
    #pragma unroll
    for (int j = 0; j < 8; ++j) {
        int n = nb + j;
        if (n < N_NODES) {
            float4 r = make_float4(acc[j][0], acc[j][1], acc[j][2], acc[j][3]);
            if (o4 < 40) *(float4*)(P + (size_t)n * 40 + o4) = r;
            else         *(float4*)(R + (size_t)n * 40 + (o4 - 40)) = r;
        }
    }
}

// final: logits = mean_agg(P[src]) + R; softmax over 40; one wave per node
__global__ __launch_bounds__(256) void k_final(
    const float* __restrict__ P, const float* __restrict__ R,
    const int* __restrict__ rowp, const int* __restrict__ col,
    const float* __restrict__ invd, float* __restrict__ out) {
    int w = blockIdx.x * 4 + (threadIdx.x >> 6);
    if (w >= N_NODES) return;
    int lane = threadIdx.x & 63;
    bool act = lane < 40;
    int beg = rowp[w], end = rowp[w + 1];
    float a0 = 0.f, a1 = 0.f, a2 = 0.f, a3 = 0.f;
    int e = beg;
    for (; e + 4 <= end; e += 4) {
        int s0 = col[e], s1 = col[e + 1], s2 = col[e + 2], s3 = col[e + 3];
        if (act) {
            a0 += P[(size_t)s0 * 40 + lane];
            a1 += P[(size_t)s1 * 40 + lane];
            a2 += P[(size_t)s2 * 40 + lane];
            a3 += P[(size_t)s3 * 40 + lane];
        }
    }
    for (; e < end; ++e) if (act) a0 += P[(size_t)col[e] * 40 + lane];
    float acc = (a0 + a1) + (a2 + a3);
    float v = act ? (acc * invd[w] + R[(size_t)w * 40 + lane]) : -1e30f;
    float m = v;
    #pragma unroll
    for (int off = 32; off; off >>= 1) m = fmaxf(m, __shfl_xor(m, off, 64));
    float ex = act ? expf(v - m) : 0.f;
    float s = ex;
    #pragma unroll
    for (int off = 32; off; off >>= 1) s += __shfl_xor(s, off, 64);
    if (act) out[(size_t)w * 40 + lane] = ex / s;
}

extern "C" void kernel_launch(void* const* d_in, const int* in_sizes, int n_in,
                              void* d_out, int out_size, void* d_ws, size_t ws_size,
                              hipStream_t stream) {
    const float* x   = (const float*)d_in[0];
    const void*  ei  = d_in[1];
    const float* Wl0 = (const float*)d_in[2];
    const float* Wr0 = (const float*)d_in[3];
    const float* b0  = (const float*)d_in[4];
    const float* Wl1 = (const float*)d_in[5];
    const float* Wr1 = (const float*)d_in[6];
    const float* b1  = (const float*)d_in[7];
    const float* Wl2 = (const float*)d_in[8];
    const float* Wr2 = (const float*)d_in[9];
    const float* b2  = (const float*)d_in[10];
    float* out = (float*)d_out;

    char* ws = (char*)d_ws;
    int*   row_ptr = (int*)(ws + WS_ROWPTR);
    int*   deg     = (int*)(ws + WS_DEG);
    int*   fill    = (int*)(ws + WS_FILL);
    float* invd    = (float*)(ws + WS_INVDEG);
    int*   bsum    = (int*)(ws + WS_BSUM);
    int*   flag    = (int*)(ws + WS_FLAG);
    float* WlT0    = (float*)(ws + WS_WLT0);
    float* WrT0    = (float*)(ws + WS_WRT0);
    float* WlT1    = (float*)(ws + WS_WLT1);
    float* WrT1    = (float*)(ws + WS_WRT1);
    float* WcT2    = (float*)(ws + WS_WCT2);
    int*   col     = (int*)(ws + WS_COL);
    float* agg     = (float*)(ws + WS_AGG);
    float* h1      = (float*)(ws + WS_H1);
    float* h2      = (float*)(ws + WS_H2);
    float* P       = (float*)(ws + WS_P);
    float* R       = (float*)(ws + WS_R);

    // zero deg + fill (adjacent)
    hipMemsetAsync(ws + WS_DEG, 0, 800768, stream);

    k_detect<<<1, 256, 0, stream>>>(ei, flag);
    k_transpose<<<64, 256, 0, stream>>>(Wl0, Wr0, Wl1, Wr1, Wl2, Wr2,
                                        WlT0, WrT0, WlT1, WrT1, WcT2);
    k_hist<<<N_EDGES / 256, 256, 0, stream>>>(ei, flag, deg);
    k_scan1<<<98, 256, 0, stream>>>(deg, bsum);
    k_scan2<<<1, 64, 0, stream>>>(bsum, row_ptr, 98);
    k_scan3<<<98, 256, 0, stream>>>(deg, bsum, row_ptr);
    k_invdeg<<<391, 256, 0, stream>>>(row_ptr, invd);
    k_scatter<<<N_EDGES / 256, 256, 0, stream>>>(ei, flag, row_ptr, fill, col);

    // layer 0
    k_aggregate<<<25000, 256, 0, stream>>>(x, row_ptr, col, invd, agg);
    k_gemm_fused<<<1563, 256, 0, stream>>>(agg, x, WlT0, WrT0, b0, h1);
    // layer 1
    k_aggregate<<<25000, 256, 0, stream>>>(h1, row_ptr, col, invd, agg);
    k_gemm_fused<<<1563, 256, 0, stream>>>(agg, h1, WlT1, WrT1, b1, h2);
    // layer 2 (GEMM first, then aggregate the 40-dim projections)
    k_gemm2<<<782, 320, 0, stream>>>(h2, WcT2, b2, P, R);
    k_final<<<25000, 256, 0, stream>>>(P, R, row_ptr, col, invd, out);
}